// Round 14
// baseline (106.288 us; speedup 1.0000x reference)
//
#include <hip/hip_runtime.h>
#include <hip/hip_bf16.h>

typedef __attribute__((ext_vector_type(8))) short bf16x8;
typedef __attribute__((ext_vector_type(16))) float f32x16;
typedef __attribute__((ext_vector_type(4))) unsigned short u16x4;
typedef __attribute__((ext_vector_type(2))) unsigned long long u64x2;

#define TT 128
#define DD 256
#define BK 64
#define BPAN 16384        // B panel offset within a 32 KiB buffer
#define PART 65536        // partials offset (after 2 buffers)
#define K2L 2.8853900817779268f   // 2*log2(e): exp(2x) = exp2(x*K2L)

// 8B-granular conflict-free panel layout (5-bit XOR key over row-pairs):
// row r (0..127), 8B slot s (0..15) ->
//   (r>>1)*256 + (((s + ((r&1)<<4)) ^ (r&31)) << 3)
__device__ __forceinline__ int poff(int r, int s) {
  return ((r >> 1) << 8) + ((((s + ((r & 1) << 4)) ^ (r & 31))) << 3);
}

__device__ __forceinline__ unsigned short f2bf(float f) {
  unsigned int x = __float_as_uint(f);
  x += 0x7fffu + ((x >> 16) & 1u);          // round-to-nearest-even
  return (unsigned short)(x >> 16);
}

__device__ __forceinline__ bf16x8 pack8(float4 lo, float4 hi) {
  bf16x8 v;
  v[0] = (short)f2bf(lo.x); v[1] = (short)f2bf(lo.y);
  v[2] = (short)f2bf(lo.z); v[3] = (short)f2bf(lo.w);
  v[4] = (short)f2bf(hi.x); v[5] = (short)f2bf(hi.y);
  v[6] = (short)f2bf(hi.z); v[7] = (short)f2bf(hi.w);
  return v;
}

// One-shot f32 -> bf16 preconversion of both feature tensors.
__global__ __launch_bounds__(256) void conv_kernel(
    const float* __restrict__ v, const float* __restrict__ w,
    unsigned short* __restrict__ vb, unsigned short* __restrict__ wb) {
  const int idx = blockIdx.x * 256 + threadIdx.x;   // float4 units
  float4 a = reinterpret_cast<const float4*>(v)[idx];
  float4 b = reinterpret_cast<const float4*>(w)[idx];
  u16x4 pa, pb;
  pa[0] = f2bf(a.x); pa[1] = f2bf(a.y); pa[2] = f2bf(a.z); pa[3] = f2bf(a.w);
  pb[0] = f2bf(b.x); pb[1] = f2bf(b.y); pb[2] = f2bf(b.z); pb[3] = f2bf(b.w);
  reinterpret_cast<u16x4*>(vb)[idx] = pa;
  reinterpret_cast<u16x4*>(wb)[idx] = pb;
}

// One workgroup (512 thr, 8 waves) per (i,j).  Dual-orientation 32x32x16
// MFMA, wave tile 64x64 (o=wid>>2, mg=row half, cg=col half) — R5's proven
// structure — with the 8B-swizzle conflict-free panels and T14 staging:
// issue global loads -> COMPUTE current buffer -> ds_write next buffer ->
// barrier.  Frag reads are ds_read_b64 pairs, 2 lanes/slot = free [m136].
template <bool PRE>
__global__ __launch_bounds__(512, 2) void pair_kernel(
    const float* __restrict__ videof, const float* __restrict__ wifif,
    const unsigned short* __restrict__ videob,
    const unsigned short* __restrict__ wifib,
    float* __restrict__ dense) {
  __shared__ __align__(16) char lds[71696];
  const int tid = threadIdx.x;
  const int bid = blockIdx.x;
  const int bi = bid >> 6, bj = bid & 63;
  const int wid = tid >> 6, l = tid & 63;
  const int l31 = l & 31;
  const int khalf = l >> 5;

  const int o  = wid >> 2;          // orientation: 0 S=video x wifi^T, 1 St
  const int mg = wid & 1;           // 64-row half of X
  const int cg = (wid >> 1) & 1;    // 64-col half of Y

  // staging indices: thread owns 32B (4 slots) of one row per operand
  const int srow = tid >> 2;
  const int sq   = tid & 3;
  const int so0  = poff(srow, sq * 4 + 0);
  const int so1  = poff(srow, sq * 4 + 1);
  const int so2  = poff(srow, sq * 4 + 2);
  const int so3  = poff(srow, sq * 4 + 3);

  f32x16 acc[2][2];
#pragma unroll
  for (int mi = 0; mi < 2; ++mi)
#pragma unroll
    for (int t = 0; t < 2; ++t)
#pragma unroll
      for (int r = 0; r < 16; ++r) acc[mi][t][r] = 0.f;

  const int xpan = o ? BPAN : 0;    // rows operand (wifi when o=1)
  const int ypan = o ? 0 : BPAN;    // cols operand
  // per-lane fragment addressing: row R -> block base (R>>1)*256 and
  // 4-bit slot XOR key KL = ((R&1)<<4) ^ (R&31) ^ (khalf<<1)
  const int RX0 = mg * 64 + l31, RX1 = RX0 + 32;
  const int RY0 = cg * 64 + l31, RY1 = RY0 + 32;
  const int PBX0 = (RX0 >> 1) << 8, PBX1 = (RX1 >> 1) << 8;
  const int PBY0 = (RY0 >> 1) << 8, PBY1 = (RY1 >> 1) << 8;
  const int KLX0 = (((RX0 & 1) << 4) ^ (RX0 & 31)) ^ (khalf << 1);
  const int KLX1 = (((RX1 & 1) << 4) ^ (RX1 & 31)) ^ (khalf << 1);
  const int KLY0 = (((RY0 & 1) << 4) ^ (RY0 & 31)) ^ (khalf << 1);
  const int KLY1 = (((RY1 & 1) << 4) ^ (RY1 & 31)) ^ (khalf << 1);

#define RD(BASE, PB, KL, KS)                                                  \
  ({                                                                          \
    const char* p_ = (BASE) + (PB);                                           \
    const int s0_ = (((KS) << 2) ^ (KL)) << 3;                                \
    u64x2 t_;                                                                 \
    t_[0] = *(const unsigned long long*)(p_ + s0_);                           \
    t_[1] = *(const unsigned long long*)(p_ + (s0_ ^ 8));                     \
    *(bf16x8*)&t_;                                                            \
  })

#define STAGE_LOAD(KP, A0, A1, B0, B1)                                        \
  do {                                                                        \
    if constexpr (PRE) {                                                      \
      const unsigned short* pa_ = videob + (size_t)bi * (TT * DD) +           \
                                  srow * DD + (KP) * BK + sq * 16;            \
      const unsigned short* pb_ = wifib + (size_t)bj * (TT * DD) +            \
                                  srow * DD + (KP) * BK + sq * 16;            \
      A0 = *(const u64x2*)(pa_);  A1 = *(const u64x2*)(pa_ + 8);              \
      B0 = *(const u64x2*)(pb_);  B1 = *(const u64x2*)(pb_ + 8);              \
    } else {                                                                  \
      const float* pa_ = videof + (size_t)bi * (TT * DD) + srow * DD +        \
                         (KP) * BK + sq * 16;                                 \
      const float* pb_ = wifif + (size_t)bj * (TT * DD) + srow * DD +         \
                         (KP) * BK + sq * 16;                                 \
      bf16x8 ta0_ = pack8(*(const float4*)(pa_), *(const float4*)(pa_ + 4));  \
      bf16x8 ta1_ = pack8(*(const float4*)(pa_ + 8), *(const float4*)(pa_ + 12)); \
      bf16x8 tb0_ = pack8(*(const float4*)(pb_), *(const float4*)(pb_ + 4));  \
      bf16x8 tb1_ = pack8(*(const float4*)(pb_ + 8), *(const float4*)(pb_ + 12)); \
      A0 = *(u64x2*)&ta0_; A1 = *(u64x2*)&ta1_;                               \
      B0 = *(u64x2*)&tb0_; B1 = *(u64x2*)&tb1_;                               \
    }                                                                         \
  } while (0)

#define STAGE_WRITE(BUF, A0, A1, B0, B1)                                      \
  do {                                                                        \
    char* ba_ = lds + (BUF) * 32768;                                          \
    *(unsigned long long*)(ba_ + so0) = A0[0];                                \
    *(unsigned long long*)(ba_ + so1) = A0[1];                                \
    *(unsigned long long*)(ba_ + so2) = A1[0];                                \
    *(unsigned long long*)(ba_ + so3) = A1[1];                                \
    *(unsigned long long*)(ba_ + BPAN + so0) = B0[0];                         \
    *(unsigned long long*)(ba_ + BPAN + so1) = B0[1];                         \
    *(unsigned long long*)(ba_ + BPAN + so2) = B1[0];                         \
    *(unsigned long long*)(ba_ + BPAN + so3) = B1[1];                         \
  } while (0)

#define COMPUTE(BUF)                                                          \
  do {                                                                        \
    const char* xb_ = lds + (BUF) * 32768 + xpan;                             \
    const char* yb_ = lds + (BUF) * 32768 + ypan;                             \
    _Pragma("unroll") for (int ks = 0; ks < 4; ++ks) {                        \
      bf16x8 x0_ = RD(xb_, PBX0, KLX0, ks);                                   \
      bf16x8 x1_ = RD(xb_, PBX1, KLX1, ks);                                   \
      bf16x8 y0_ = RD(yb_, PBY0, KLY0, ks);                                   \
      bf16x8 y1_ = RD(yb_, PBY1, KLY1, ks);                                   \
      acc[0][0] = __builtin_amdgcn_mfma_f32_32x32x16_bf16(x0_, y0_, acc[0][0], 0, 0, 0); \
      acc[0][1] = __builtin_amdgcn_mfma_f32_32x32x16_bf16(x0_, y1_, acc[0][1], 0, 0, 0); \
      acc[1][0] = __builtin_amdgcn_mfma_f32_32x32x16_bf16(x1_, y0_, acc[1][0], 0, 0, 0); \
      acc[1][1] = __builtin_amdgcn_mfma_f32_32x32x16_bf16(x1_, y1_, acc[1][1], 0, 0, 0); \
    }                                                                         \
  } while (0)

  // ---- prologue: stage panel 0 into buf0 ----
  {
    u64x2 a0, a1, b0, b1;
    STAGE_LOAD(0, a0, a1, b0, b1);
    STAGE_WRITE(0, a0, a1, b0, b1);
  }
  __syncthreads();

  // ---- K loop: T14 split (issue loads | compute | write | barrier) ----
#pragma unroll
  for (int kp = 0; kp < 4; ++kp) {
    u64x2 a0, a1, b0, b1;
    if (kp < 3) STAGE_LOAD(kp + 1, a0, a1, b0, b1);
    COMPUTE(kp & 1);
    if (kp < 3) STAGE_WRITE((kp + 1) & 1, a0, a1, b0, b1);
    __syncthreads();
  }

  // ---- pooling partials: PM/PS/PV [o][mg][128 cols] ----
  float* PM = (float*)(lds + PART);
  float* PS = PM + 512;
  float* PV = PM + 1024;
  float* Gb = PM + 1536;

#pragma unroll
  for (int t = 0; t < 2; ++t) {
    float mx = acc[0][t][0];
#pragma unroll
    for (int r = 1; r < 16; ++r) mx = fmaxf(mx, acc[0][t][r]);
#pragma unroll
    for (int r = 0; r < 16; ++r) mx = fmaxf(mx, acc[1][t][r]);
    const float mxk = mx * K2L;
    float se = 0.f, sv = 0.f;
#pragma unroll
    for (int mi = 0; mi < 2; ++mi)
#pragma unroll
      for (int r = 0; r < 16; ++r) {
        const float v = acc[mi][t][r];
        const float e = exp2f(fmaf(v, K2L, -mxk));
        se += e;
        sv = fmaf(e, v, sv);
      }
    const float om = __shfl_xor(mx, 32);
    const float os = __shfl_xor(se, 32);
    const float ov = __shfl_xor(sv, 32);
    const float M  = fmaxf(mx, om);
    const float f1 = exp2f((mx - M) * K2L);
    const float f2 = exp2f((om - M) * K2L);
    se = fmaf(se, f1, os * f2);
    sv = fmaf(sv, f1, ov * f2);
    if (l < 32) {
      const int idx = o * 256 + mg * 128 + cg * 64 + t * 32 + l;
      PM[idx] = M; PS[idx] = se; PV[idx] = sv;
    }
  }
  __syncthreads();

  // merge the two 64-row halves per column -> soft_sim value (into PM)
  if (tid < 256) {
    const int o2 = tid >> 7, c = tid & 127;
    const int i0 = o2 * 256 + c, i1 = i0 + 128;
    const float m0 = PM[i0], m1 = PM[i1];
    const float M  = fmaxf(m0, m1);
    const float f0 = exp2f((m0 - M) * K2L);
    const float f1 = exp2f((m1 - M) * K2L);
    const float s  = fmaf(PS[i0], f0, PS[i1] * f1);
    const float v  = fmaf(PV[i0], f0, PV[i1] * f1);
    PM[i0] = v / s;
  }
  __syncthreads();

  // frame-level softmax pooling -> scalars
  // wave 0: v2w (cols = video frames -> o=1 partials); wave 1: w2v (o=0)
  if (wid < 2) {
    const float* RS = PM + (wid == 0 ? 256 : 0);
    float a0 = RS[l], a1 = RS[64 + l];
    float mx = fmaxf(a0, a1);
#pragma unroll
    for (int s = 1; s < 64; s <<= 1) mx = fmaxf(mx, __shfl_xor(mx, s));
    float e0 = exp2f((a0 - mx) * K2L), e1 = exp2f((a1 - mx) * K2L);
    float se = e0 + e1, sev = fmaf(e0, a0, e1 * a1);
#pragma unroll
    for (int s = 1; s < 64; s <<= 1) { se += __shfl_xor(se, s); sev += __shfl_xor(sev, s); }
    if (l == 0) Gb[wid] = sev / se;
  }
  __syncthreads();
  if (tid == 0) dense[bid] = 0.5f * (Gb[0] + Gb[1]);
}

// Label-smoothed symmetric CE over the 64x64 dense-similarity matrix. f32 out.
__global__ __launch_bounds__(64) void loss_kernel(
    const float* __restrict__ dense, const float* __restrict__ scalep,
    float* __restrict__ out) {
  const int i = threadIdx.x;
  const float sc = fminf(scalep[0], 40.0f);
  float mxr = -3.4e38f, mxc = -3.4e38f;
  for (int j = 0; j < 64; ++j) {
    mxr = fmaxf(mxr, sc * dense[i * 64 + j]);
    mxc = fmaxf(mxc, sc * dense[j * 64 + i]);
  }
  float ser = 0.f, sec = 0.f, slr = 0.f, slc = 0.f;
  for (int j = 0; j < 64; ++j) {
    float zr = sc * dense[i * 64 + j];
    float zc = sc * dense[j * 64 + i];
    ser += __expf(zr - mxr); sec += __expf(zc - mxc);
    slr += zr;               slc += zc;
  }
  const float lser = mxr + logf(ser);
  const float lsec = mxc + logf(sec);
  const float zd = sc * dense[i * 65];
  float lv = lser - 0.9f * zd - 0.1f * (slr * (1.0f / 64.0f));
  float lw = lsec - 0.9f * zd - 0.1f * (slc * (1.0f / 64.0f));
  float t = 0.5f * (lv + lw);
#pragma unroll
  for (int s = 1; s < 64; s <<= 1) t += __shfl_xor(t, s);
  if (i == 0) out[0] = t * (1.0f / 64.0f);
}

extern "C" void kernel_launch(void* const* d_in, const int* in_sizes, int n_in,
                              void* d_out, int out_size, void* d_ws, size_t ws_size,
                              hipStream_t stream) {
  (void)in_sizes; (void)n_in; (void)out_size;
  const float* video = (const float*)d_in[0];
  const float* wifi  = (const float*)d_in[1];
  const float* scale = (const float*)d_in[2];
  float* dense = (float*)d_ws;                                   // 16 KiB
  unsigned short* vb = (unsigned short*)((char*)d_ws + 16384);   // 4 MiB
  unsigned short* wb = vb + 64 * TT * DD;                        // 4 MiB

  const bool pre = ws_size >= (size_t)16384 + 2u * 64 * TT * DD * 2;
  if (pre) {
    hipLaunchKernelGGL(conv_kernel, dim3(2048), dim3(256), 0, stream,
                       video, wifi, vb, wb);
    hipLaunchKernelGGL((pair_kernel<true>), dim3(64 * 64), dim3(512), 0, stream,
                       video, wifi, vb, wb, dense);
  } else {
    hipLaunchKernelGGL((pair_kernel<false>), dim3(64 * 64), dim3(512), 0, stream,
                       video, wifi, vb, wb, dense);
  }
  hipLaunchKernelGGL(loss_kernel, dim3(1), dim3(64), 0, stream,
                     dense, scale, (float*)d_out);
}